// Round 2
// baseline (770.048 us; speedup 1.0000x reference)
//
#include <hip/hip_runtime.h>
#include <hip/hip_bf16.h>
#include <math.h>

typedef __attribute__((ext_vector_type(8))) short short8;   // 8 bf16 (4 VGPRs)
typedef __attribute__((ext_vector_type(4))) float f32x4;    // MFMA C/D

namespace {
constexpr int E_TOTAL = 500000;
constexpr int ND  = 128;   // node dim
constexpr int ED  = 64;    // edge dim
constexpr int KIN = 320;   // 2*ND + ED
constexpr int H   = 128;   // hidden
constexpr int ME  = 64;    // edges per block
constexpr int RS  = 264;   // catA row stride (shorts): 256 data + 8 skew (528B = +4 banks/row)
constexpr float EPS = 1e-5f;
// d_ws offsets (in shorts): weights transposed [n][k], bf16
constexpr int OFF_W1T = 0;       // [128][320]
constexpr int OFF_WGT = 40960;   // [128][320]
constexpr int OFF_W2T = 81920;   // [128][128]
constexpr int OFF_WRT = 98304;   // [128][64]
}

__device__ __forceinline__ unsigned short f2bf(float f) {
  union { __hip_bfloat16 h; unsigned short u; } cv;
  cv.h = __float2bfloat16(f);   // RNE
  return cv.u;
}
__device__ __forceinline__ unsigned pack2(float a, float b) {
  return (unsigned)f2bf(a) | ((unsigned)f2bf(b) << 16);
}

// exact GELU via branch-free Abramowitz-Stegun 7.1.26 erf (|err| <= 1.5e-7).
// ~16 VALU ops, no divergence (vs branchy OCML erff).
__device__ __forceinline__ float gelu_erf(float x) {
  const float s = x * 0.70710678118654752f;
  const float a = fabsf(s);
  const float t = __builtin_amdgcn_rcpf(fmaf(0.3275911f, a, 1.0f));
  float p = fmaf(1.061405429f, t, -1.453152027f);
  p = fmaf(p, t, 1.421413741f);
  p = fmaf(p, t, -0.284496736f);
  p = fmaf(p, t, 0.254829592f);
  p = p * t;
  const float e = __expf(-a * a);
  float er = fmaf(-p, e, 1.0f);          // erf(|s|)
  er = copysignf(er, s);
  return 0.5f * x * (1.0f + er);
}

// Build a bf16 MFMA A-fragment (8 consecutive k's) from a global fp32 ea row.
__device__ __forceinline__ short8 ea_frag(const float* __restrict__ er, int kk) {
  const float4 f0 = *(const float4*)(er + kk);
  const float4 f1 = *(const float4*)(er + kk + 4);
  union { short8 s; unsigned u[4]; } cv;
  cv.u[0] = pack2(f0.x, f0.y);
  cv.u[1] = pack2(f0.z, f0.w);
  cv.u[2] = pack2(f1.x, f1.y);
  cv.u[3] = pack2(f1.z, f1.w);
  return cv.s;
}

// One-shot (per launch) weight prep: fp32 [K][N] -> bf16 transposed [N][K] in ws.
__global__ void prep_weights(const float* __restrict__ W1, const float* __restrict__ Wg,
                             const float* __restrict__ W2, const float* __restrict__ Wr,
                             short* __restrict__ wt) {
  const int t = blockIdx.x * 256 + threadIdx.x;
  if (t < 40960) {                       // W1T / WgT: n in [0,128), k in [0,320)
    const int n = t / KIN, k = t % KIN;
    wt[OFF_W1T + t] = (short)f2bf(W1[k * H + n]);
    wt[OFF_WGT + t] = (short)f2bf(Wg[k * H + n]);
  }
  if (t < 16384) {                       // W2T: [128][128]
    const int n = t / H, k = t % H;
    wt[OFF_W2T + t] = (short)f2bf(W2[k * H + n]);
  }
  if (t < 8192) {                        // WrT: [128][64]
    const int n = t / ED, k = t % ED;
    wt[OFF_WRT + t] = (short)f2bf(Wr[k * H + n]);
  }
}

// Block: 256 threads = 4 waves, 64 edges. Wave w owns cols [32w, 32w+32) (2 N-tiles)
// for ALL 4 M-tiles. catA: bf16 [m][k<256] = [x_src | x_dst]; ea A-frags built from
// global fp32 on the fly. Rows k<128 reused for h after GEMM1.
// Register discipline for __launch_bounds__(256,4) (128 unified regs/wave):
//  - peak accumulator usage capped at 64 (accH+accG in GEMM1; accU+accG in GEMM2's
//    W2 part; R is MFMA'd INTO the gated accU, so no separate accR),
//  - per-mt A-fragment loads (4 live regs, not 16),
//  - ea rows as 32-bit element offsets vs the uniform base (no pointer quads).
__global__ __launch_bounds__(256, 4) void edge_mfma_kernel(
    const float* __restrict__ x, const int* __restrict__ ei, const float* __restrict__ ea,
    const short* __restrict__ wt,
    const float* __restrict__ b1, const float* __restrict__ g1, const float* __restrict__ be1,
    const float* __restrict__ b2, const float* __restrict__ bg, const float* __restrict__ br,
    const float* __restrict__ g2, const float* __restrict__ be2,
    float* __restrict__ out)
{
  __shared__ short catA[ME * RS];   // 33792 B
  __shared__ float red[ME][8];      // per-row {s,q} x 4 waves
  __shared__ int   sidx[ME], didx[ME];

  const int t    = threadIdx.x;
  const int w    = t >> 6;
  const int lane = t & 63;
  const int g    = lane >> 4;   // quad
  const int l15  = lane & 15;
  const long e0  = (long)blockIdx.x * ME;

  if (t < ME) {
    long eg = e0 + t; if (eg >= E_TOTAL) eg = E_TOTAL - 1;
    sidx[t] = ei[eg];
  } else if (t < 2 * ME) {
    long eg = e0 + (t - ME); if (eg >= E_TOTAL) eg = E_TOTAL - 1;
    didx[t - ME] = ei[E_TOTAL + eg];
  }
  __syncthreads();

  // ---- gather: catA[e][k] = bf16([x[src] | x[dst]]) ; float4 loads, 2 edges/wave/iter ----
  {
    const int esub = lane >> 5;          // 0..1
    const int c    = (lane & 31) << 2;   // 0,4,...,124
    for (int i = 0; i < 8; ++i) {
      const int e = i * 8 + w * 2 + esub;
      const float4 xs = *(const float4*)(x + (long)sidx[e] * ND + c);
      const float4 xd = *(const float4*)(x + (long)didx[e] * ND + c);
      uint2 ps, pd;
      ps.x = pack2(xs.x, xs.y); ps.y = pack2(xs.z, xs.w);
      pd.x = pack2(xd.x, xd.y); pd.y = pack2(xd.z, xd.w);
      *(uint2*)&catA[e * RS + c]      = ps;
      *(uint2*)&catA[e * RS + ND + c] = pd;
    }
  }

  // per-lane ea row element-offsets (row = mt*16 + l15), reused in GEMM2-R
  int eaOff[4];
  #pragma unroll
  for (int mt = 0; mt < 4; ++mt) {
    long eg = e0 + mt * 16 + l15; if (eg >= E_TOTAL) eg = E_TOTAL - 1;
    eaOff[mt] = (int)(eg * ED);
  }
  __syncthreads();

  const int col0 = w * 32 + l15;        // N-tile 0 col
  const int col1 = w * 32 + 16 + l15;   // N-tile 1 col

  // ---- GEMM1: h_pre = cat@W1 + b1 ; g_pre = cat@Wg + bg ----
  f32x4 accH[4][2], accG[4][2];
  {
    const float bh0 = b1[col0], bh1 = b1[col1];
    const float bg0 = bg[col0], bg1 = bg[col1];
    #pragma unroll
    for (int mt = 0; mt < 4; ++mt) {
      accH[mt][0] = (f32x4){bh0, bh0, bh0, bh0};
      accH[mt][1] = (f32x4){bh1, bh1, bh1, bh1};
      accG[mt][0] = (f32x4){bg0, bg0, bg0, bg0};
      accG[mt][1] = (f32x4){bg1, bg1, bg1, bg1};
    }
  }
  {
    const short* pW1a = wt + OFF_W1T + col0 * KIN + g * 8;
    const short* pW1b = wt + OFF_W1T + col1 * KIN + g * 8;
    const short* pWga = wt + OFF_WGT + col0 * KIN + g * 8;
    const short* pWgb = wt + OFF_WGT + col1 * KIN + g * 8;
    // x part: k = 0..256 from LDS
    for (int ks = 0; ks < 8; ++ks) {
      const int ko = ks * 32 + g * 8;
      const short8 bW1a = *(const short8*)(pW1a + ks * 32);
      const short8 bW1b = *(const short8*)(pW1b + ks * 32);
      const short8 bWga = *(const short8*)(pWga + ks * 32);
      const short8 bWgb = *(const short8*)(pWgb + ks * 32);
      #pragma unroll
      for (int mt = 0; mt < 4; ++mt) {
        const short8 a = *(const short8*)&catA[(mt * 16 + l15) * RS + ko];
        accH[mt][0] = __builtin_amdgcn_mfma_f32_16x16x32_bf16(a, bW1a, accH[mt][0], 0, 0, 0);
        accH[mt][1] = __builtin_amdgcn_mfma_f32_16x16x32_bf16(a, bW1b, accH[mt][1], 0, 0, 0);
        accG[mt][0] = __builtin_amdgcn_mfma_f32_16x16x32_bf16(a, bWga, accG[mt][0], 0, 0, 0);
        accG[mt][1] = __builtin_amdgcn_mfma_f32_16x16x32_bf16(a, bWgb, accG[mt][1], 0, 0, 0);
      }
    }
    // ea part: k = 256..320, A-frags straight from global fp32 (L2-hot)
    #pragma unroll
    for (int ks = 0; ks < 2; ++ks) {
      const int kk = ks * 32 + g * 8;
      const short8 bW1a = *(const short8*)(pW1a + (8 + ks) * 32);
      const short8 bW1b = *(const short8*)(pW1b + (8 + ks) * 32);
      const short8 bWga = *(const short8*)(pWga + (8 + ks) * 32);
      const short8 bWgb = *(const short8*)(pWgb + (8 + ks) * 32);
      #pragma unroll
      for (int mt = 0; mt < 4; ++mt) {
        const short8 am = ea_frag(ea + eaOff[mt], kk);
        accH[mt][0] = __builtin_amdgcn_mfma_f32_16x16x32_bf16(am, bW1a, accH[mt][0], 0, 0, 0);
        accH[mt][1] = __builtin_amdgcn_mfma_f32_16x16x32_bf16(am, bW1b, accH[mt][1], 0, 0, 0);
        accG[mt][0] = __builtin_amdgcn_mfma_f32_16x16x32_bf16(am, bWga, accG[mt][0], 0, 0, 0);
        accG[mt][1] = __builtin_amdgcn_mfma_f32_16x16x32_bf16(am, bWgb, accG[mt][1], 0, 0, 0);
      }
    }
  }

  // ---- LN1 stats: rows r = mt*16 + g*4 + reg; reduce wave's 32 cols then cross-wave ----
  #pragma unroll
  for (int mt = 0; mt < 4; ++mt) {
    f32x4 ps = accH[mt][0] + accH[mt][1];
    f32x4 pq = accH[mt][0] * accH[mt][0] + accH[mt][1] * accH[mt][1];
    #pragma unroll
    for (int off = 1; off < 16; off <<= 1) {
      #pragma unroll
      for (int r = 0; r < 4; ++r) {
        ps[r] += __shfl_xor(ps[r], off);
        pq[r] += __shfl_xor(pq[r], off);
      }
    }
    if (l15 == 0) {
      #pragma unroll
      for (int r = 0; r < 4; ++r) {
        red[mt * 16 + g * 4 + r][w * 2]     = ps[r];
        red[mt * 16 + g * 4 + r][w * 2 + 1] = pq[r];
      }
    }
  }
  __syncthreads();   // B1 — also orders all GEMM1 catA reads before h overwrite

  // ---- LN1 apply + exact GELU -> h to LDS (alias x[src] rows); sigmoid gate in regs ----
  {
    const float g1v0 = g1[col0], g1v1 = g1[col1];
    const float be10 = be1[col0], be11 = be1[col1];
    #pragma unroll
    for (int mt = 0; mt < 4; ++mt) {
      #pragma unroll
      for (int r = 0; r < 4; ++r) {
        const int row = mt * 16 + g * 4 + r;
        const float4 ra = *(const float4*)&red[row][0];
        const float4 rb = *(const float4*)&red[row][4];
        const float sum = ra.x + ra.z + rb.x + rb.z;
        const float sq  = ra.y + ra.w + rb.y + rb.w;
        const float m   = sum * (1.0f / H);
        float var = sq * (1.0f / H) - m * m;
        var = fmaxf(var, 0.0f);
        const float rs = __builtin_amdgcn_rsqf(var + EPS);
        float h0 = (accH[mt][0][r] - m) * rs * g1v0 + be10;
        float h1 = (accH[mt][1][r] - m) * rs * g1v1 + be11;
        h0 = gelu_erf(h0);
        h1 = gelu_erf(h1);
        catA[row * RS + col0] = (short)f2bf(h0);
        catA[row * RS + col1] = (short)f2bf(h1);
        accG[mt][0][r] = __builtin_amdgcn_rcpf(1.0f + __expf(-accG[mt][0][r]));
        accG[mt][1][r] = __builtin_amdgcn_rcpf(1.0f + __expf(-accG[mt][1][r]));
      }
    }
  }
  __syncthreads();   // B2

  // ---- GEMM2: U = h@W2 + b2 ; then in-place gate; then accumulate R = ea@Wr ----
  f32x4 accU[4][2];
  {
    const float bu0 = b2[col0], bu1 = b2[col1];
    #pragma unroll
    for (int mt = 0; mt < 4; ++mt) {
      accU[mt][0] = (f32x4){bu0, bu0, bu0, bu0};
      accU[mt][1] = (f32x4){bu1, bu1, bu1, bu1};
    }
  }
  {
    const short* pW2a = wt + OFF_W2T + col0 * H + g * 8;
    const short* pW2b = wt + OFF_W2T + col1 * H + g * 8;
    for (int ks = 0; ks < H / 32; ++ks) {
      const int ko = ks * 32 + g * 8;
      const short8 b0  = *(const short8*)(pW2a + ks * 32);
      const short8 b1v = *(const short8*)(pW2b + ks * 32);
      #pragma unroll
      for (int mt = 0; mt < 4; ++mt) {
        const short8 a = *(const short8*)&catA[(mt * 16 + l15) * RS + ko];
        accU[mt][0] = __builtin_amdgcn_mfma_f32_16x16x32_bf16(a, b0,  accU[mt][0], 0, 0, 0);
        accU[mt][1] = __builtin_amdgcn_mfma_f32_16x16x32_bf16(a, b1v, accU[mt][1], 0, 0, 0);
      }
    }
  }
  // gate in place: accU = U*sigmoid + br ; accG dies here (frees 32 regs before Wr MFMAs)
  {
    const float br0 = br[col0], br1 = br[col1];
    const f32x4 vbr0 = (f32x4){br0, br0, br0, br0};
    const f32x4 vbr1 = (f32x4){br1, br1, br1, br1};
    #pragma unroll
    for (int mt = 0; mt < 4; ++mt) {
      accU[mt][0] = accU[mt][0] * accG[mt][0] + vbr0;
      accU[mt][1] = accU[mt][1] * accG[mt][1] + vbr1;
    }
  }
  // R part: accumulate ea@Wr into the gated accU via MFMA C-in
  {
    const short* pWra = wt + OFF_WRT + col0 * ED + g * 8;
    const short* pWrb = wt + OFF_WRT + col1 * ED + g * 8;
    #pragma unroll
    for (int ks = 0; ks < 2; ++ks) {
      const int kk = ks * 32 + g * 8;
      const short8 b0  = *(const short8*)(pWra + ks * 32);
      const short8 b1v = *(const short8*)(pWrb + ks * 32);
      #pragma unroll
      for (int mt = 0; mt < 4; ++mt) {
        const short8 am = ea_frag(ea + eaOff[mt], kk);
        accU[mt][0] = __builtin_amdgcn_mfma_f32_16x16x32_bf16(am, b0,  accU[mt][0], 0, 0, 0);
        accU[mt][1] = __builtin_amdgcn_mfma_f32_16x16x32_bf16(am, b1v, accU[mt][1], 0, 0, 0);
      }
    }
  }

  // ---- LN2 ----
  #pragma unroll
  for (int mt = 0; mt < 4; ++mt) {
    f32x4 ps = accU[mt][0] + accU[mt][1];
    f32x4 pq = accU[mt][0] * accU[mt][0] + accU[mt][1] * accU[mt][1];
    #pragma unroll
    for (int off = 1; off < 16; off <<= 1) {
      #pragma unroll
      for (int r = 0; r < 4; ++r) {
        ps[r] += __shfl_xor(ps[r], off);
        pq[r] += __shfl_xor(pq[r], off);
      }
    }
    if (l15 == 0) {
      #pragma unroll
      for (int r = 0; r < 4; ++r) {
        red[mt * 16 + g * 4 + r][w * 2]     = ps[r];
        red[mt * 16 + g * 4 + r][w * 2 + 1] = pq[r];
      }
    }
  }
  __syncthreads();   // B3
  {
    const float g2v0 = g2[col0], g2v1 = g2[col1];
    const float be20 = be2[col0], be21 = be2[col1];
    #pragma unroll
    for (int mt = 0; mt < 4; ++mt) {
      #pragma unroll
      for (int r = 0; r < 4; ++r) {
        const int row = mt * 16 + g * 4 + r;
        const float4 ra = *(const float4*)&red[row][0];
        const float4 rb = *(const float4*)&red[row][4];
        const float sum = ra.x + ra.z + rb.x + rb.z;
        const float sq  = ra.y + ra.w + rb.y + rb.w;
        const float m   = sum * (1.0f / H);
        float var = sq * (1.0f / H) - m * m;
        var = fmaxf(var, 0.0f);
        const float rs = __builtin_amdgcn_rsqf(var + EPS);
        const long eg = e0 + row;
        if (eg < E_TOTAL) {
          out[eg * H + col0] = (accU[mt][0][r] - m) * rs * g2v0 + be20;
          out[eg * H + col1] = (accU[mt][1][r] - m) * rs * g2v1 + be21;
        }
      }
    }
  }
}

extern "C" void kernel_launch(void* const* d_in, const int* in_sizes, int n_in,
                              void* d_out, int out_size, void* d_ws, size_t ws_size,
                              hipStream_t stream) {
  const float* x   = (const float*)d_in[0];
  const int*   ei  = (const int*)  d_in[1];
  const float* ea  = (const float*)d_in[2];
  const float* W1  = (const float*)d_in[3];
  const float* b1  = (const float*)d_in[4];
  const float* g1  = (const float*)d_in[5];
  const float* be1 = (const float*)d_in[6];
  const float* W2  = (const float*)d_in[7];
  const float* b2  = (const float*)d_in[8];
  const float* Wg  = (const float*)d_in[9];
  const float* bg  = (const float*)d_in[10];
  const float* Wr  = (const float*)d_in[11];
  const float* br  = (const float*)d_in[12];
  const float* g2  = (const float*)d_in[13];
  const float* be2 = (const float*)d_in[14];
  float* out = (float*)d_out;
  short* wt  = (short*)d_ws;   // 212992 B used

  prep_weights<<<160, 256, 0, stream>>>(W1, Wg, W2, Wr, wt);

  const int grid = (E_TOTAL + ME - 1) / ME;   // 7813
  edge_mfma_kernel<<<grid, 256, 0, stream>>>(
      x, ei, ea, wt, b1, g1, be1, b2, bg, br, g2, be2, out);
}

// Round 3
// 622.848 us; speedup vs baseline: 1.2363x; 1.2363x over previous
//
#include <hip/hip_runtime.h>
#include <hip/hip_bf16.h>
#include <math.h>

typedef __attribute__((ext_vector_type(8))) short short8;   // 8 bf16 (4 VGPRs)
typedef __attribute__((ext_vector_type(4))) float f32x4;    // MFMA C/D

namespace {
constexpr int E_TOTAL = 500000;
constexpr int ND  = 128;   // node dim
constexpr int ED  = 64;    // edge dim
constexpr int KIN = 320;   // 2*ND + ED
constexpr int H   = 128;   // hidden
constexpr int ME  = 64;    // edges per block
constexpr int RS  = 328;   // catA row stride (shorts): 656B = 16B-aligned, +4-bank skew
constexpr float EPS = 1e-5f;
// d_ws offsets (in shorts): weights transposed [n][k], bf16
constexpr int OFF_W1T = 0;       // [128][320]
constexpr int OFF_WGT = 40960;   // [128][320]
constexpr int OFF_W2T = 81920;   // [128][128]
constexpr int OFF_WRT = 98304;   // [128][64]
}

__device__ __forceinline__ unsigned short f2bf(float f) {
  union { __hip_bfloat16 h; unsigned short u; } cv;
  cv.h = __float2bfloat16(f);   // RNE
  return cv.u;
}
__device__ __forceinline__ unsigned pack2(float a, float b) {
  return (unsigned)f2bf(a) | ((unsigned)f2bf(b) << 16);
}

// exact GELU via branch-free Abramowitz-Stegun 7.1.26 erf (|err| <= 1.5e-7).
// ~16 VALU ops, no divergence (vs branchy OCML erff ~50+ ops under divergence).
// Verified both prior rounds: VALUBusy per-wave work dropped exactly as modeled.
__device__ __forceinline__ float gelu_erf(float x) {
  const float s = x * 0.70710678118654752f;
  const float a = fabsf(s);
  const float t = __builtin_amdgcn_rcpf(fmaf(0.3275911f, a, 1.0f));
  float p = fmaf(1.061405429f, t, -1.453152027f);
  p = fmaf(p, t, 1.421413741f);
  p = fmaf(p, t, -0.284496736f);
  p = fmaf(p, t, 0.254829592f);
  p = p * t;
  const float e = __expf(-a * a);
  float er = fmaf(-p, e, 1.0f);          // erf(|s|)
  er = copysignf(er, s);
  return 0.5f * x * (1.0f + er);
}

// One-shot (per launch) weight prep: fp32 [K][N] -> bf16 transposed [N][K] in ws.
__global__ void prep_weights(const float* __restrict__ W1, const float* __restrict__ Wg,
                             const float* __restrict__ W2, const float* __restrict__ Wr,
                             short* __restrict__ wt) {
  const int t = blockIdx.x * 256 + threadIdx.x;
  if (t < 40960) {                       // W1T / WgT: n in [0,128), k in [0,320)
    const int n = t / KIN, k = t % KIN;
    wt[OFF_W1T + t] = (short)f2bf(W1[k * H + n]);
    wt[OFF_WGT + t] = (short)f2bf(Wg[k * H + n]);
  }
  if (t < 16384) {                       // W2T: [128][128]
    const int n = t / H, k = t % H;
    wt[OFF_W2T + t] = (short)f2bf(W2[k * H + n]);
  }
  if (t < 8192) {                        // WrT: [128][64]
    const int n = t / ED, k = t % ED;
    wt[OFF_WRT + t] = (short)f2bf(Wr[k * H + n]);
  }
}

// Block: 256 threads = 4 waves, 64 edges. Wave w owns cols [32w, 32w+32) (2 N-tiles)
// for ALL 4 M-tiles -> each weight element is read exactly once per block (L2-resident).
// catA: bf16 [m][k] A-fragment layout (full 320-col row incl. staged ea); rows k<128
// reused for h after GEMM1.
// REGISTER REGIME (lesson of rounds 1-2): no forced occupancy. (256,4)'s 128-reg cap
// spilled 130-220 MB each way to scratch (WRITE_SIZE 250->381->469 MB) and throttled
// MFMA issue. (256,2) lets the allocator run spill-free at ~3 blocks/CU, which is the
// LDS limit anyway (44.5 KB). accR is folded into gated accU via MFMA C-in so peak
// accumulator pressure is 64 regs in both GEMMs.
__global__ __launch_bounds__(256, 2) void edge_mfma_kernel(
    const float* __restrict__ x, const int* __restrict__ ei, const float* __restrict__ ea,
    const short* __restrict__ wt,
    const float* __restrict__ b1, const float* __restrict__ g1, const float* __restrict__ be1,
    const float* __restrict__ b2, const float* __restrict__ bg, const float* __restrict__ br,
    const float* __restrict__ g2, const float* __restrict__ be2,
    float* __restrict__ out)
{
  __shared__ short catA[ME * RS];   // 41984 B
  __shared__ float red[ME][8];      // per-row {s,q} x 4 waves
  __shared__ int   sidx[ME], didx[ME];

  const int t    = threadIdx.x;
  const int w    = t >> 6;
  const int lane = t & 63;
  const int g    = lane >> 4;   // quad
  const int l15  = lane & 15;
  const long e0  = (long)blockIdx.x * ME;

  if (t < ME) {
    long eg = e0 + t; if (eg >= E_TOTAL) eg = E_TOTAL - 1;
    sidx[t] = ei[eg];
  } else if (t < 2 * ME) {
    long eg = e0 + (t - ME); if (eg >= E_TOTAL) eg = E_TOTAL - 1;
    didx[t - ME] = ei[E_TOTAL + eg];
  }
  __syncthreads();

  // ---- gather: catA[e][k] = bf16([x[src] | x[dst] | ea]) ----
  {
    const int c = lane << 1;                  // 0..126, float2 per lane = full row per wave
    for (int i = 0; i < 16; ++i) {
      const int e = i * 4 + w;
      const float2 xs = *(const float2*)(x + (long)sidx[e] * ND + c);
      const float2 xd = *(const float2*)(x + (long)didx[e] * ND + c);
      *(unsigned*)&catA[e * RS + c]      = pack2(xs.x, xs.y);
      *(unsigned*)&catA[e * RS + ND + c] = pack2(xd.x, xd.y);
    }
    const int e8 = t >> 5;
    const int c2 = (t & 31) << 1;
    for (int i = 0; i < 8; ++i) {
      const int e = i * 8 + e8;
      long eg = e0 + e; if (eg >= E_TOTAL) eg = E_TOTAL - 1;
      const float2 v = *(const float2*)(ea + eg * ED + c2);
      *(unsigned*)&catA[e * RS + 2 * ND + c2] = pack2(v.x, v.y);
    }
  }
  __syncthreads();

  const int col0 = w * 32 + l15;        // N-tile 0 col
  const int col1 = w * 32 + 16 + l15;   // N-tile 1 col

  // ---- GEMM1: h_pre = cat@W1 + b1 ; g_pre = cat@Wg + bg ----
  f32x4 accH[4][2], accG[4][2];
  {
    const float bh0 = b1[col0], bh1 = b1[col1];
    const float bg0 = bg[col0], bg1 = bg[col1];
    #pragma unroll
    for (int mt = 0; mt < 4; ++mt) {
      accH[mt][0] = (f32x4){bh0, bh0, bh0, bh0};
      accH[mt][1] = (f32x4){bh1, bh1, bh1, bh1};
      accG[mt][0] = (f32x4){bg0, bg0, bg0, bg0};
      accG[mt][1] = (f32x4){bg1, bg1, bg1, bg1};
    }
  }
  {
    const short* pW1a = wt + OFF_W1T + col0 * KIN + g * 8;
    const short* pW1b = wt + OFF_W1T + col1 * KIN + g * 8;
    const short* pWga = wt + OFF_WGT + col0 * KIN + g * 8;
    const short* pWgb = wt + OFF_WGT + col1 * KIN + g * 8;
    for (int ks = 0; ks < KIN / 32; ++ks) {
      const int ko = ks * 32 + g * 8;
      short8 a[4];
      #pragma unroll
      for (int mt = 0; mt < 4; ++mt)
        a[mt] = *(const short8*)&catA[(mt * 16 + l15) * RS + ko];
      const short8 bW1a = *(const short8*)(pW1a + ks * 32);
      const short8 bW1b = *(const short8*)(pW1b + ks * 32);
      const short8 bWga = *(const short8*)(pWga + ks * 32);
      const short8 bWgb = *(const short8*)(pWgb + ks * 32);
      #pragma unroll
      for (int mt = 0; mt < 4; ++mt) {
        accH[mt][0] = __builtin_amdgcn_mfma_f32_16x16x32_bf16(a[mt], bW1a, accH[mt][0], 0, 0, 0);
        accH[mt][1] = __builtin_amdgcn_mfma_f32_16x16x32_bf16(a[mt], bW1b, accH[mt][1], 0, 0, 0);
        accG[mt][0] = __builtin_amdgcn_mfma_f32_16x16x32_bf16(a[mt], bWga, accG[mt][0], 0, 0, 0);
        accG[mt][1] = __builtin_amdgcn_mfma_f32_16x16x32_bf16(a[mt], bWgb, accG[mt][1], 0, 0, 0);
      }
    }
  }

  // ---- LN1 stats: rows r = mt*16 + g*4 + reg; reduce wave's 32 cols then cross-wave ----
  #pragma unroll
  for (int mt = 0; mt < 4; ++mt) {
    f32x4 ps = accH[mt][0] + accH[mt][1];
    f32x4 pq = accH[mt][0] * accH[mt][0] + accH[mt][1] * accH[mt][1];
    #pragma unroll
    for (int off = 1; off < 16; off <<= 1) {
      #pragma unroll
      for (int r = 0; r < 4; ++r) {
        ps[r] += __shfl_xor(ps[r], off);
        pq[r] += __shfl_xor(pq[r], off);
      }
    }
    if (l15 == 0) {
      #pragma unroll
      for (int r = 0; r < 4; ++r) {
        red[mt * 16 + g * 4 + r][w * 2]     = ps[r];
        red[mt * 16 + g * 4 + r][w * 2 + 1] = pq[r];
      }
    }
  }
  __syncthreads();   // B1 — also orders all GEMM1 catA reads before h overwrite

  // ---- LN1 apply + exact GELU -> h to LDS (alias x[src] rows); sigmoid gate in regs ----
  {
    const float g1v0 = g1[col0], g1v1 = g1[col1];
    const float be10 = be1[col0], be11 = be1[col1];
    #pragma unroll
    for (int mt = 0; mt < 4; ++mt) {
      #pragma unroll
      for (int r = 0; r < 4; ++r) {
        const int row = mt * 16 + g * 4 + r;
        const float4 ra = *(const float4*)&red[row][0];
        const float4 rb = *(const float4*)&red[row][4];
        const float sum = ra.x + ra.z + rb.x + rb.z;
        const float sq  = ra.y + ra.w + rb.y + rb.w;
        const float m   = sum * (1.0f / H);
        float var = sq * (1.0f / H) - m * m;
        var = fmaxf(var, 0.0f);
        const float rs = __builtin_amdgcn_rsqf(var + EPS);
        float h0 = (accH[mt][0][r] - m) * rs * g1v0 + be10;
        float h1 = (accH[mt][1][r] - m) * rs * g1v1 + be11;
        h0 = gelu_erf(h0);
        h1 = gelu_erf(h1);
        catA[row * RS + col0] = (short)f2bf(h0);
        catA[row * RS + col1] = (short)f2bf(h1);
        accG[mt][0][r] = __builtin_amdgcn_rcpf(1.0f + __expf(-accG[mt][0][r]));
        accG[mt][1][r] = __builtin_amdgcn_rcpf(1.0f + __expf(-accG[mt][1][r]));
      }
    }
  }
  __syncthreads();   // B2

  // ---- GEMM2: U = h@W2 + b2 ; gate in place ; accumulate R = ea@Wr into gated U ----
  f32x4 accU[4][2];
  {
    const float bu0 = b2[col0], bu1 = b2[col1];
    #pragma unroll
    for (int mt = 0; mt < 4; ++mt) {
      accU[mt][0] = (f32x4){bu0, bu0, bu0, bu0};
      accU[mt][1] = (f32x4){bu1, bu1, bu1, bu1};
    }
  }
  {
    const short* pW2a = wt + OFF_W2T + col0 * H + g * 8;
    const short* pW2b = wt + OFF_W2T + col1 * H + g * 8;
    for (int ks = 0; ks < H / 32; ++ks) {
      const int ko = ks * 32 + g * 8;
      short8 a[4];
      #pragma unroll
      for (int mt = 0; mt < 4; ++mt)
        a[mt] = *(const short8*)&catA[(mt * 16 + l15) * RS + ko];
      const short8 b0  = *(const short8*)(pW2a + ks * 32);
      const short8 b1v = *(const short8*)(pW2b + ks * 32);
      #pragma unroll
      for (int mt = 0; mt < 4; ++mt) {
        accU[mt][0] = __builtin_amdgcn_mfma_f32_16x16x32_bf16(a[mt], b0,  accU[mt][0], 0, 0, 0);
        accU[mt][1] = __builtin_amdgcn_mfma_f32_16x16x32_bf16(a[mt], b1v, accU[mt][1], 0, 0, 0);
      }
    }
  }
  // gate in place: accU = U*sigmoid + br ; accG dies here (frees 32 acc regs)
  {
    const float br0 = br[col0], br1 = br[col1];
    const f32x4 vbr0 = (f32x4){br0, br0, br0, br0};
    const f32x4 vbr1 = (f32x4){br1, br1, br1, br1};
    #pragma unroll
    for (int mt = 0; mt < 4; ++mt) {
      accU[mt][0] = accU[mt][0] * accG[mt][0] + vbr0;
      accU[mt][1] = accU[mt][1] * accG[mt][1] + vbr1;
    }
  }
  // R part: ea@Wr accumulated via MFMA C-in (ea rows staged in catA cols 256..320)
  {
    const short* pWra = wt + OFF_WRT + col0 * ED + g * 8;
    const short* pWrb = wt + OFF_WRT + col1 * ED + g * 8;
    #pragma unroll
    for (int ks = 0; ks < 2; ++ks) {
      const int ko = 2 * ND + ks * 32 + g * 8;
      short8 a[4];
      #pragma unroll
      for (int mt = 0; mt < 4; ++mt)
        a[mt] = *(const short8*)&catA[(mt * 16 + l15) * RS + ko];
      const short8 b0  = *(const short8*)(pWra + ks * 32);
      const short8 b1v = *(const short8*)(pWrb + ks * 32);
      #pragma unroll
      for (int mt = 0; mt < 4; ++mt) {
        accU[mt][0] = __builtin_amdgcn_mfma_f32_16x16x32_bf16(a[mt], b0,  accU[mt][0], 0, 0, 0);
        accU[mt][1] = __builtin_amdgcn_mfma_f32_16x16x32_bf16(a[mt], b1v, accU[mt][1], 0, 0, 0);
      }
    }
  }

  // ---- LN2 ----
  #pragma unroll
  for (int mt = 0; mt < 4; ++mt) {
    f32x4 ps = accU[mt][0] + accU[mt][1];
    f32x4 pq = accU[mt][0] * accU[mt][0] + accU[mt][1] * accU[mt][1];
    #pragma unroll
    for (int off = 1; off < 16; off <<= 1) {
      #pragma unroll
      for (int r = 0; r < 4; ++r) {
        ps[r] += __shfl_xor(ps[r], off);
        pq[r] += __shfl_xor(pq[r], off);
      }
    }
    if (l15 == 0) {
      #pragma unroll
      for (int r = 0; r < 4; ++r) {
        red[mt * 16 + g * 4 + r][w * 2]     = ps[r];
        red[mt * 16 + g * 4 + r][w * 2 + 1] = pq[r];
      }
    }
  }
  __syncthreads();   // B3
  {
    const float g2v0 = g2[col0], g2v1 = g2[col1];
    const float be20 = be2[col0], be21 = be2[col1];
    #pragma unroll
    for (int mt = 0; mt < 4; ++mt) {
      #pragma unroll
      for (int r = 0; r < 4; ++r) {
        const int row = mt * 16 + g * 4 + r;
        const float4 ra = *(const float4*)&red[row][0];
        const float4 rb = *(const float4*)&red[row][4];
        const float sum = ra.x + ra.z + rb.x + rb.z;
        const float sq  = ra.y + ra.w + rb.y + rb.w;
        const float m   = sum * (1.0f / H);
        float var = sq * (1.0f / H) - m * m;
        var = fmaxf(var, 0.0f);
        const float rs = __builtin_amdgcn_rsqf(var + EPS);
        const long eg = e0 + row;
        if (eg < E_TOTAL) {
          out[eg * H + col0] = (accU[mt][0][r] - m) * rs * g2v0 + be20;
          out[eg * H + col1] = (accU[mt][1][r] - m) * rs * g2v1 + be21;
        }
      }
    }
  }
}

extern "C" void kernel_launch(void* const* d_in, const int* in_sizes, int n_in,
                              void* d_out, int out_size, void* d_ws, size_t ws_size,
                              hipStream_t stream) {
  const float* x   = (const float*)d_in[0];
  const int*   ei  = (const int*)  d_in[1];
  const float* ea  = (const float*)d_in[2];
  const float* W1  = (const float*)d_in[3];
  const float* b1  = (const float*)d_in[4];
  const float* g1  = (const float*)d_in[5];
  const float* be1 = (const float*)d_in[6];
  const float* W2  = (const float*)d_in[7];
  const float* b2  = (const float*)d_in[8];
  const float* Wg  = (const float*)d_in[9];
  const float* bg  = (const float*)d_in[10];
  const float* Wr  = (const float*)d_in[11];
  const float* br  = (const float*)d_in[12];
  const float* g2  = (const float*)d_in[13];
  const float* be2 = (const float*)d_in[14];
  float* out = (float*)d_out;
  short* wt  = (short*)d_ws;   // 212992 B used

  prep_weights<<<160, 256, 0, stream>>>(W1, Wg, W2, Wr, wt);

  const int grid = (E_TOTAL + ME - 1) / ME;   // 7813
  edge_mfma_kernel<<<grid, 256, 0, stream>>>(
      x, ei, ea, wt, b1, g1, be1, b2, bg, br, g2, be2, out);
}